// Round 1
// baseline (201.868 us; speedup 1.0000x reference)
//
#include <hip/hip_runtime.h>
#include <hip/hip_bf16.h>
#include <stdint.h>
#include <stddef.h>

typedef __bf16 bf16x8 __attribute__((ext_vector_type(8)));
typedef __bf16 bf16x4 __attribute__((ext_vector_type(4)));
typedef float  f32x4  __attribute__((ext_vector_type(4)));

// ---------------- cast float -> bf16, 4 elements/thread ----------------
__global__ __launch_bounds__(256) void cast4_kernel(const float* __restrict__ in,
                                                    __bf16* __restrict__ out, int n4) {
  int i = blockIdx.x * 256 + threadIdx.x;
  if (i >= n4) return;
  float4 f = ((const float4*)in)[i];
  bf16x4 v;
  v[0] = (__bf16)f.x; v[1] = (__bf16)f.y; v[2] = (__bf16)f.z; v[3] = (__bf16)f.w;
  ((bf16x4*)out)[i] = v;
}

// ---------------- transpose 512x512 f32 -> bf16 : out[c][k] = in[k][c] ----------------
__global__ __launch_bounds__(256) void transpose_cast_kernel(const float* __restrict__ in,
                                                             __bf16* __restrict__ out) {
  __shared__ float ls[64][65];
  int tc = blockIdx.x * 64;   // input col tile
  int tr = blockIdx.y * 64;   // input row tile
  int tid = threadIdx.x;
#pragma unroll
  for (int i = 0; i < 16; ++i) {
    int e = tid + i * 256;
    int r = e >> 6, c = e & 63;
    ls[r][c] = in[(size_t)(tr + r) * 512 + tc + c];
  }
  __syncthreads();
#pragma unroll
  for (int i = 0; i < 16; ++i) {
    int e = tid + i * 256;
    int r = e >> 6, c = e & 63;
    out[(size_t)(tc + r) * 512 + tr + c] = (__bf16)ls[c][r];
  }
}

// ---------------- pair bias: pb[h][n][m] = sum_p pf[n][m][p] * Wp[p][h] ----------------
__global__ __launch_bounds__(256) void pair_bias_kernel(const float* __restrict__ pf,
                                                        const float* __restrict__ Wp,
                                                        __bf16* __restrict__ pb) {
  __shared__ float wps[512];
  int tid = threadIdx.x;
  wps[tid] = Wp[tid];
  wps[tid + 256] = Wp[tid + 256];
  __syncthreads();
  size_t idx = (size_t)blockIdx.x * 256 + tid;   // (n,m) flat index, 0..1M
  const float* row = pf + idx * 64;
  float acc[8] = {0.f,0.f,0.f,0.f,0.f,0.f,0.f,0.f};
#pragma unroll
  for (int p4 = 0; p4 < 16; ++p4) {
    float4 f = ((const float4*)row)[p4];
    const float* fv = (const float*)&f;
#pragma unroll
    for (int u = 0; u < 4; ++u) {
      float x = fv[u];
      int p = p4 * 4 + u;
#pragma unroll
      for (int h = 0; h < 8; ++h) acc[h] += x * wps[p * 8 + h];
    }
  }
#pragma unroll
  for (int h = 0; h < 8; ++h)
    pb[((size_t)h << 20) + idx] = (__bf16)acc[h];
}

// ---------------- shared 128x128 GEMM mainloop: acc = A[m0:+128,:] * Bt[n0:+128,:]^T ----------------
__device__ __forceinline__ void gemm_mainloop_128(const __bf16* __restrict__ A,
                                                  const __bf16* __restrict__ Bt,
                                                  int K, int m0, int n0,
                                                  f32x4 (&acc)[4][4]) {
  __shared__ __bf16 As[128][40];   // +8 pad, 16B-aligned rows
  __shared__ __bf16 Bs[128][40];
  int tid = threadIdx.x;
  int wave = tid >> 6, lane = tid & 63;
  int wm = (wave >> 1) * 64, wn = (wave & 1) * 64;
  int lg = lane >> 4, lr = lane & 15;
#pragma unroll
  for (int i = 0; i < 4; ++i)
#pragma unroll
    for (int j = 0; j < 4; ++j) acc[i][j] = (f32x4){0.f, 0.f, 0.f, 0.f};

  for (int k0 = 0; k0 < K; k0 += 32) {
    __syncthreads();
#pragma unroll
    for (int i = 0; i < 2; ++i) {
      int cid = tid + i * 256;
      int row = cid >> 2, c8 = (cid & 3) * 8;
      *(bf16x8*)&As[row][c8] = *(const bf16x8*)&A[(size_t)(m0 + row) * K + k0 + c8];
      *(bf16x8*)&Bs[row][c8] = *(const bf16x8*)&Bt[(size_t)(n0 + row) * K + k0 + c8];
    }
    __syncthreads();
    bf16x8 af[4], bfr[4];
#pragma unroll
    for (int i = 0; i < 4; ++i) {
      af[i]  = *(const bf16x8*)&As[wm + i * 16 + lr][lg * 8];
      bfr[i] = *(const bf16x8*)&Bs[wn + i * 16 + lr][lg * 8];
    }
#pragma unroll
    for (int i = 0; i < 4; ++i)
#pragma unroll
      for (int j = 0; j < 4; ++j)
        acc[i][j] = __builtin_amdgcn_mfma_f32_16x16x32_bf16(af[i], bfr[j], acc[i][j], 0, 0, 0);
  }
}

// ---------------- fused QKV projection GEMM: [4096,512] x [512,1536] ----------------
__global__ __launch_bounds__(256) void qkv_gemm_kernel(const __bf16* __restrict__ A,
                                                       const __bf16* __restrict__ Bt,
                                                       const float* __restrict__ bq,
                                                       const float* __restrict__ bk,
                                                       const float* __restrict__ bv,
                                                       __bf16* __restrict__ qb,
                                                       __bf16* __restrict__ kb,
                                                       __bf16* __restrict__ vb) {
  int m0 = blockIdx.y * 128, n0 = blockIdx.x * 128;
  f32x4 acc[4][4];
  gemm_mainloop_128(A, Bt, 512, m0, n0, acc);
  int tid = threadIdx.x, wave = tid >> 6, lane = tid & 63;
  int wm = (wave >> 1) * 64, wn = (wave & 1) * 64, lg = lane >> 4, lr = lane & 15;
#pragma unroll
  for (int i = 0; i < 4; ++i)
#pragma unroll
    for (int j = 0; j < 4; ++j)
#pragma unroll
      for (int r = 0; r < 4; ++r) {
        int grow = m0 + wm + i * 16 + lg * 4 + r;   // 0..4095  (b*1024+n)
        int gcol = n0 + wn + j * 16 + lr;           // 0..1535
        int sel = gcol >> 9, c = gcol & 511;
        float bias = (sel == 0 ? bq : sel == 1 ? bk : bv)[c];
        float val = acc[i][j][r] + bias;
        __bf16* dst = sel == 0 ? qb : sel == 1 ? kb : vb;
        int hh = c >> 6, dd = c & 63;
        int b = grow >> 10, n = grow & 1023;
        dst[(((size_t)(b * 8 + hh)) * 1024 + n) * 64 + dd] = (__bf16)val;
      }
}

// ---------------- V transpose: [bh][n][d] -> [bh][d][n] ----------------
__global__ __launch_bounds__(256) void vtrans_kernel(const __bf16* __restrict__ v,
                                                     __bf16* __restrict__ vt) {
  __shared__ __bf16 ls[64][72];
  int bh = blockIdx.y;
  int n0 = blockIdx.x * 64;
  int tid = threadIdx.x;
#pragma unroll
  for (int i = 0; i < 2; ++i) {
    int cid = tid + i * 256;
    int row = cid >> 3, c8 = (cid & 7) * 8;
    *(bf16x8*)&ls[row][c8] = *(const bf16x8*)&v[(((size_t)bh) * 1024 + n0 + row) * 64 + c8];
  }
  __syncthreads();
#pragma unroll
  for (int i = 0; i < 2; ++i) {
    int cid = tid + i * 256;
    int drow = cid >> 3, n8 = (cid & 7) * 8;
    bf16x8 val;
#pragma unroll
    for (int j = 0; j < 8; ++j) val[j] = ls[n8 + j][drow];
    *(bf16x8*)&vt[((size_t)bh * 64 + drow) * 1024 + n0 + n8] = val;
  }
}

// ---------------- flash attention with additive pair bias ----------------
__global__ __launch_bounds__(256) void flash_kernel(const __bf16* __restrict__ qg,
                                                    const __bf16* __restrict__ kg,
                                                    const __bf16* __restrict__ vtg,
                                                    const __bf16* __restrict__ pbg,
                                                    __bf16* __restrict__ merged) {
  __shared__ __bf16 pbs[128][72];      // bias tile [128 q][64 k]
  __shared__ __bf16 pls[4][32][72];    // per-wave P tile [32 q][64 k]
  int bh = blockIdx.y, b = bh >> 3, h = bh & 7;
  int q0 = blockIdx.x * 128;
  int tid = threadIdx.x, wave = tid >> 6, lane = tid & 63;
  int lg = lane >> 4, lr = lane & 15;
  const __bf16* qp = qg + (size_t)bh * 1024 * 64;
  const __bf16* kp = kg + (size_t)bh * 1024 * 64;
  const __bf16* vp = vtg + (size_t)bh * 64 * 1024;
  const __bf16* pbh = pbg + ((size_t)h << 20);

  int qw0 = q0 + wave * 32;
  bf16x8 qf[2][2];
#pragma unroll
  for (int mf = 0; mf < 2; ++mf)
#pragma unroll
    for (int c = 0; c < 2; ++c)
      qf[mf][c] = *(const bf16x8*)&qp[(size_t)(qw0 + mf * 16 + lr) * 64 + c * 32 + lg * 8];

  float mrow[2][4], lrow[2][4];
  f32x4 of[2][4] = {};
#pragma unroll
  for (int mf = 0; mf < 2; ++mf)
#pragma unroll
    for (int r = 0; r < 4; ++r) { mrow[mf][r] = -1e30f; lrow[mf][r] = 0.f; }

  const float scale = 0.125f;

  for (int kb2 = 0; kb2 < 16; ++kb2) {
    __syncthreads();
    // stage bias tile
#pragma unroll
    for (int i = 0; i < 4; ++i) {
      int cid = tid + i * 256;
      int row = cid >> 3, c8 = (cid & 7) * 8;
      *(bf16x8*)&pbs[row][c8] = *(const bf16x8*)&pbh[(size_t)(q0 + row) * 1024 + kb2 * 64 + c8];
    }
    __syncthreads();

    // K fragments + S = Q K^T
    bf16x8 kf[4][2];
#pragma unroll
    for (int nf = 0; nf < 4; ++nf)
#pragma unroll
      for (int c = 0; c < 2; ++c)
        kf[nf][c] = *(const bf16x8*)&kp[(size_t)(kb2 * 64 + nf * 16 + lr) * 64 + c * 32 + lg * 8];

    f32x4 sv[2][4];
#pragma unroll
    for (int mf = 0; mf < 2; ++mf)
#pragma unroll
      for (int nf = 0; nf < 4; ++nf) {
        f32x4 z = {0.f, 0.f, 0.f, 0.f};
        z = __builtin_amdgcn_mfma_f32_16x16x32_bf16(qf[mf][0], kf[nf][0], z, 0, 0, 0);
        z = __builtin_amdgcn_mfma_f32_16x16x32_bf16(qf[mf][1], kf[nf][1], z, 0, 0, 0);
        sv[mf][nf] = z;
      }

    // scale + bias
#pragma unroll
    for (int mf = 0; mf < 2; ++mf)
#pragma unroll
      for (int nf = 0; nf < 4; ++nf)
#pragma unroll
        for (int r = 0; r < 4; ++r) {
          float bias = (float)pbs[wave * 32 + mf * 16 + lg * 4 + r][nf * 16 + lr];
          sv[mf][nf][r] = sv[mf][nf][r] * scale + bias;
        }

    // online softmax per q-row (rows live at (lg*4+r); cols across lr and nf)
#pragma unroll
    for (int mf = 0; mf < 2; ++mf)
#pragma unroll
      for (int r = 0; r < 4; ++r) {
        float tm = fmaxf(fmaxf(sv[mf][0][r], sv[mf][1][r]), fmaxf(sv[mf][2][r], sv[mf][3][r]));
#pragma unroll
        for (int x = 1; x < 16; x <<= 1) tm = fmaxf(tm, __shfl_xor(tm, x));
        float newm = fmaxf(mrow[mf][r], tm);
        float fs = __expf(mrow[mf][r] - newm);
        mrow[mf][r] = newm;
        float rs = 0.f;
#pragma unroll
        for (int nf = 0; nf < 4; ++nf) {
          float p = __expf(sv[mf][nf][r] - newm);
          sv[mf][nf][r] = p;
          rs += p;
        }
#pragma unroll
        for (int x = 1; x < 16; x <<= 1) rs += __shfl_xor(rs, x);
        lrow[mf][r] = lrow[mf][r] * fs + rs;
#pragma unroll
        for (int dn = 0; dn < 4; ++dn) of[mf][dn][r] *= fs;
      }

    // write P to per-wave LDS (re-layout D-frag -> A-frag)
#pragma unroll
    for (int mf = 0; mf < 2; ++mf)
#pragma unroll
      for (int nf = 0; nf < 4; ++nf)
#pragma unroll
        for (int r = 0; r < 4; ++r)
          pls[wave][mf * 16 + lg * 4 + r][nf * 16 + lr] = (__bf16)sv[mf][nf][r];
    __syncthreads();

    // PV
    bf16x8 pa[2][2], vf[4][2];
#pragma unroll
    for (int mf = 0; mf < 2; ++mf)
#pragma unroll
      for (int c = 0; c < 2; ++c)
        pa[mf][c] = *(const bf16x8*)&pls[wave][mf * 16 + lr][c * 32 + lg * 8];
#pragma unroll
    for (int dn = 0; dn < 4; ++dn)
#pragma unroll
      for (int c = 0; c < 2; ++c)
        vf[dn][c] = *(const bf16x8*)&vp[(size_t)(dn * 16 + lr) * 1024 + kb2 * 64 + c * 32 + lg * 8];
#pragma unroll
    for (int mf = 0; mf < 2; ++mf)
#pragma unroll
      for (int dn = 0; dn < 4; ++dn) {
        of[mf][dn] = __builtin_amdgcn_mfma_f32_16x16x32_bf16(pa[mf][0], vf[dn][0], of[mf][dn], 0, 0, 0);
        of[mf][dn] = __builtin_amdgcn_mfma_f32_16x16x32_bf16(pa[mf][1], vf[dn][1], of[mf][dn], 0, 0, 0);
      }
  }

  // epilogue: normalize and store merged [b*N+n][h*64+dd]
#pragma unroll
  for (int mf = 0; mf < 2; ++mf)
#pragma unroll
    for (int dn = 0; dn < 4; ++dn)
#pragma unroll
      for (int r = 0; r < 4; ++r) {
        int n = qw0 + mf * 16 + lg * 4 + r;
        int dd = dn * 16 + lr;
        float val = of[mf][dn][r] / lrow[mf][r];
        merged[((size_t)(b * 1024 + n)) * 512 + h * 64 + dd] = (__bf16)val;
      }
}

// ---------------- output projection GEMM: fp32 out + bias ----------------
__global__ __launch_bounds__(256) void out_gemm_kernel(const __bf16* __restrict__ A,
                                                       const __bf16* __restrict__ Bt,
                                                       const float* __restrict__ bo,
                                                       float* __restrict__ out) {
  int m0 = blockIdx.y * 128, n0 = blockIdx.x * 128;
  f32x4 acc[4][4];
  gemm_mainloop_128(A, Bt, 512, m0, n0, acc);
  int tid = threadIdx.x, wave = tid >> 6, lane = tid & 63;
  int wm = (wave >> 1) * 64, wn = (wave & 1) * 64, lg = lane >> 4, lr = lane & 15;
#pragma unroll
  for (int i = 0; i < 4; ++i)
#pragma unroll
    for (int j = 0; j < 4; ++j)
#pragma unroll
      for (int r = 0; r < 4; ++r) {
        int grow = m0 + wm + i * 16 + lg * 4 + r;
        int gcol = n0 + wn + j * 16 + lr;
        out[(size_t)grow * 512 + gcol] = acc[i][j][r] + bo[gcol];
      }
}

extern "C" void kernel_launch(void* const* d_in, const int* in_sizes, int n_in,
                              void* d_out, int out_size, void* d_ws, size_t ws_size,
                              hipStream_t stream) {
  const float* tokens = (const float*)d_in[0];
  const float* pf     = (const float*)d_in[1];
  const float* Wq     = (const float*)d_in[2];
  const float* bq     = (const float*)d_in[3];
  const float* Wk     = (const float*)d_in[4];
  const float* bk     = (const float*)d_in[5];
  const float* Wv     = (const float*)d_in[6];
  const float* bv     = (const float*)d_in[7];
  const float* Wo     = (const float*)d_in[8];
  const float* bo     = (const float*)d_in[9];
  // d_in[10] = Wp
  const float* Wp     = (const float*)d_in[10];
  float* out = (float*)d_out;

  char* ws = (char*)d_ws;
  size_t off = 0;
  auto alloc = [&](size_t bytes) { char* p = ws + off; off += (bytes + 255) & ~(size_t)255; return p; };
  __bf16* tok_bf = (__bf16*)alloc((size_t)4096 * 512 * 2);
  __bf16* WcatT  = (__bf16*)alloc((size_t)1536 * 512 * 2);
  __bf16* WoT    = (__bf16*)alloc((size_t)512 * 512 * 2);
  __bf16* qb     = (__bf16*)alloc((size_t)32 * 1024 * 64 * 2);
  __bf16* kb     = (__bf16*)alloc((size_t)32 * 1024 * 64 * 2);
  __bf16* vb     = (__bf16*)alloc((size_t)32 * 1024 * 64 * 2);
  __bf16* vtb    = (__bf16*)alloc((size_t)32 * 64 * 1024 * 2);
  __bf16* pbb    = (__bf16*)alloc((size_t)8 * 1024 * 1024 * 2);
  __bf16* merged = (__bf16*)alloc((size_t)4096 * 512 * 2);

  cast4_kernel<<<2048, 256, 0, stream>>>(tokens, tok_bf, 4096 * 512 / 4);
  transpose_cast_kernel<<<dim3(8, 8), 256, 0, stream>>>(Wq, WcatT);
  transpose_cast_kernel<<<dim3(8, 8), 256, 0, stream>>>(Wk, WcatT + 512 * 512);
  transpose_cast_kernel<<<dim3(8, 8), 256, 0, stream>>>(Wv, WcatT + 2 * 512 * 512);
  transpose_cast_kernel<<<dim3(8, 8), 256, 0, stream>>>(Wo, WoT);
  pair_bias_kernel<<<4096, 256, 0, stream>>>(pf, Wp, pbb);
  qkv_gemm_kernel<<<dim3(12, 32), 256, 0, stream>>>(tok_bf, WcatT, bq, bk, bv, qb, kb, vb);
  vtrans_kernel<<<dim3(16, 32), 256, 0, stream>>>(vb, vtb);
  flash_kernel<<<dim3(8, 32), 256, 0, stream>>>(qb, kb, vtb, pbb, merged);
  out_gemm_kernel<<<dim3(4, 32), 256, 0, stream>>>(merged, WoT, bo, out);
}

// Round 2
// 164.722 us; speedup vs baseline: 1.2255x; 1.2255x over previous
//
#include <hip/hip_runtime.h>
#include <hip/hip_bf16.h>
#include <stdint.h>
#include <stddef.h>

typedef __bf16 bf16x8 __attribute__((ext_vector_type(8)));
typedef __bf16 bf16x4 __attribute__((ext_vector_type(4)));
typedef float  f32x4  __attribute__((ext_vector_type(4)));

#define PAIR_BLOCKS 4096
#define CAST_BLOCKS 2048
#define TR_BLOCKS   256

// ---------------- fused prep: pair_bias + tokens cast + weight transposes ----------------
// pair_bias: pb[h][n][m] = sum_p pf[n][m][p] * Wp[p][h], coalesced via LDS staging.
__global__ __launch_bounds__(256) void prep_kernel(
    const float* __restrict__ tokens, const float* __restrict__ pf,
    const float* __restrict__ Wq, const float* __restrict__ Wk,
    const float* __restrict__ Wv, const float* __restrict__ Wo,
    const float* __restrict__ Wp,
    __bf16* __restrict__ tok_bf, __bf16* __restrict__ WcatT,
    __bf16* __restrict__ WoT, __bf16* __restrict__ pbb) {
  __shared__ __align__(16) float smem[256 * 66 + 512];
  int bx = blockIdx.x, tid = threadIdx.x;
  if (bx < PAIR_BLOCKS) {
    float* wps = &smem[256 * 66];
    wps[tid] = Wp[tid];
    wps[tid + 256] = Wp[tid + 256];
    // coalesced stage: 256 rows x 64 f32 = 4096 float4, lane-contiguous
    const float4* src = (const float4*)(pf + (size_t)bx * 256 * 64);
#pragma unroll
    for (int k = 0; k < 16; ++k) {
      int f = tid + k * 256;
      int row = f >> 4, p4 = f & 15;
      float4 v = src[f];
      *(float2*)&smem[row * 66 + p4 * 4]     = (float2){v.x, v.y};
      *(float2*)&smem[row * 66 + p4 * 4 + 2] = (float2){v.z, v.w};
    }
    __syncthreads();
    const float* myrow = &smem[tid * 66];   // bank (2*tid+p)%32 -> 2-way = free
    float acc[8] = {0.f,0.f,0.f,0.f,0.f,0.f,0.f,0.f};
#pragma unroll
    for (int p = 0; p < 64; ++p) {
      float x = myrow[p];
#pragma unroll
      for (int h = 0; h < 8; ++h) acc[h] += x * wps[p * 8 + h];
    }
    size_t idx = (size_t)bx * 256 + tid;
#pragma unroll
    for (int h = 0; h < 8; ++h)
      pbb[((size_t)h << 20) + idx] = (__bf16)acc[h];
  } else if (bx < PAIR_BLOCKS + CAST_BLOCKS) {
    int i = (bx - PAIR_BLOCKS) * 256 + tid;
    float4 f = ((const float4*)tokens)[i];
    bf16x4 v;
    v[0] = (__bf16)f.x; v[1] = (__bf16)f.y; v[2] = (__bf16)f.z; v[3] = (__bf16)f.w;
    ((bf16x4*)tok_bf)[i] = v;
  } else {
    int t = bx - (PAIR_BLOCKS + CAST_BLOCKS);
    int which = t >> 6; t &= 63;
    const float* in = which == 0 ? Wq : which == 1 ? Wk : which == 2 ? Wv : Wo;
    __bf16* out = which < 3 ? (WcatT + (size_t)which * 512 * 512) : WoT;
    float (*ls)[65] = (float(*)[65])smem;
    int tc = (t & 7) * 64, tr = (t >> 3) * 64;
#pragma unroll
    for (int i = 0; i < 16; ++i) {
      int e = tid + i * 256, r = e >> 6, c = e & 63;
      ls[r][c] = in[(size_t)(tr + r) * 512 + tc + c];
    }
    __syncthreads();
#pragma unroll
    for (int i = 0; i < 16; ++i) {
      int e = tid + i * 256, r = e >> 6, c = e & 63;
      out[(size_t)(tc + r) * 512 + tr + c] = (__bf16)ls[c][r];
    }
  }
}

// ---------------- shared 128x128 GEMM mainloop: acc = A[m0:+128,:] * Bt[n0:+128,:]^T ----------------
__device__ __forceinline__ void gemm_mainloop_128(const __bf16* __restrict__ A,
                                                  const __bf16* __restrict__ Bt,
                                                  int K, int m0, int n0,
                                                  f32x4 (&acc)[4][4]) {
  __shared__ __bf16 As[128][40];   // +8 pad, 16B-aligned rows
  __shared__ __bf16 Bs[128][40];
  int tid = threadIdx.x;
  int wave = tid >> 6, lane = tid & 63;
  int wm = (wave >> 1) * 64, wn = (wave & 1) * 64;
  int lg = lane >> 4, lr = lane & 15;
#pragma unroll
  for (int i = 0; i < 4; ++i)
#pragma unroll
    for (int j = 0; j < 4; ++j) acc[i][j] = (f32x4){0.f, 0.f, 0.f, 0.f};

  for (int k0 = 0; k0 < K; k0 += 32) {
    __syncthreads();
#pragma unroll
    for (int i = 0; i < 2; ++i) {
      int cid = tid + i * 256;
      int row = cid >> 2, c8 = (cid & 3) * 8;
      *(bf16x8*)&As[row][c8] = *(const bf16x8*)&A[(size_t)(m0 + row) * K + k0 + c8];
      *(bf16x8*)&Bs[row][c8] = *(const bf16x8*)&Bt[(size_t)(n0 + row) * K + k0 + c8];
    }
    __syncthreads();
    bf16x8 af[4], bfr[4];
#pragma unroll
    for (int i = 0; i < 4; ++i) {
      af[i]  = *(const bf16x8*)&As[wm + i * 16 + lr][lg * 8];
      bfr[i] = *(const bf16x8*)&Bs[wn + i * 16 + lr][lg * 8];
    }
#pragma unroll
    for (int i = 0; i < 4; ++i)
#pragma unroll
      for (int j = 0; j < 4; ++j)
        acc[i][j] = __builtin_amdgcn_mfma_f32_16x16x32_bf16(af[i], bfr[j], acc[i][j], 0, 0, 0);
  }
}

// ---------------- fused QKV projection GEMM: [4096,512] x [512,1536] ----------------
// V is written directly transposed: vtb[bh][d][n]
__global__ __launch_bounds__(256) void qkv_gemm_kernel(const __bf16* __restrict__ A,
                                                       const __bf16* __restrict__ Bt,
                                                       const float* __restrict__ bq,
                                                       const float* __restrict__ bk,
                                                       const float* __restrict__ bv,
                                                       __bf16* __restrict__ qb,
                                                       __bf16* __restrict__ kb,
                                                       __bf16* __restrict__ vtb) {
  int m0 = blockIdx.y * 128, n0 = blockIdx.x * 128;
  f32x4 acc[4][4];
  gemm_mainloop_128(A, Bt, 512, m0, n0, acc);
  int tid = threadIdx.x, wave = tid >> 6, lane = tid & 63;
  int wm = (wave >> 1) * 64, wn = (wave & 1) * 64, lg = lane >> 4, lr = lane & 15;
#pragma unroll
  for (int i = 0; i < 4; ++i)
#pragma unroll
    for (int j = 0; j < 4; ++j) {
      int grow0 = m0 + wm + i * 16 + lg * 4;     // b*1024+n, base of 4 consecutive n
      int gcol = n0 + wn + j * 16 + lr;          // 0..1535
      int sel = gcol >> 9, c = gcol & 511;
      int hh = c >> 6, dd = c & 63;
      int b = grow0 >> 10, n = grow0 & 1023;
      if (sel == 2) {
        float bias = bv[c];
        bf16x4 pack;
#pragma unroll
        for (int r = 0; r < 4; ++r) pack[r] = (__bf16)(acc[i][j][r] + bias);
        *(bf16x4*)&vtb[(((size_t)(b * 8 + hh)) * 64 + dd) * 1024 + n] = pack;
      } else {
        float bias = (sel == 0 ? bq : bk)[c];
        __bf16* dst = sel == 0 ? qb : kb;
#pragma unroll
        for (int r = 0; r < 4; ++r)
          dst[(((size_t)(b * 8 + hh)) * 1024 + n + r) * 64 + dd] = (__bf16)(acc[i][j][r] + bias);
      }
    }
}

// ---------------- flash attention with additive pair bias ----------------
__global__ __launch_bounds__(256) void flash_kernel(const __bf16* __restrict__ qg,
                                                    const __bf16* __restrict__ kg,
                                                    const __bf16* __restrict__ vtg,
                                                    const __bf16* __restrict__ pbg,
                                                    __bf16* __restrict__ merged) {
  __shared__ __bf16 pbs[128][72];      // bias tile [128 q][64 k]
  __shared__ __bf16 pls[4][32][72];    // per-wave P tile [32 q][64 k]
  int bh = blockIdx.y, b = bh >> 3, h = bh & 7;
  int q0 = blockIdx.x * 128;
  int tid = threadIdx.x, wave = tid >> 6, lane = tid & 63;
  int lg = lane >> 4, lr = lane & 15;
  const __bf16* qp = qg + (size_t)bh * 1024 * 64;
  const __bf16* kp = kg + (size_t)bh * 1024 * 64;
  const __bf16* vp = vtg + (size_t)bh * 64 * 1024;
  const __bf16* pbh = pbg + ((size_t)h << 20);

  int qw0 = q0 + wave * 32;
  bf16x8 qf[2][2];
#pragma unroll
  for (int mf = 0; mf < 2; ++mf)
#pragma unroll
    for (int c = 0; c < 2; ++c)
      qf[mf][c] = *(const bf16x8*)&qp[(size_t)(qw0 + mf * 16 + lr) * 64 + c * 32 + lg * 8];

  float mrow[2][4], lrow[2][4];
  f32x4 of[2][4] = {};
#pragma unroll
  for (int mf = 0; mf < 2; ++mf)
#pragma unroll
    for (int r = 0; r < 4; ++r) { mrow[mf][r] = -1e30f; lrow[mf][r] = 0.f; }

  const float scale = 0.125f;

  for (int kb2 = 0; kb2 < 16; ++kb2) {
    __syncthreads();
    // stage bias tile
#pragma unroll
    for (int i = 0; i < 4; ++i) {
      int cid = tid + i * 256;
      int row = cid >> 3, c8 = (cid & 7) * 8;
      *(bf16x8*)&pbs[row][c8] = *(const bf16x8*)&pbh[(size_t)(q0 + row) * 1024 + kb2 * 64 + c8];
    }
    __syncthreads();

    // K fragments + S = Q K^T
    bf16x8 kf[4][2];
#pragma unroll
    for (int nf = 0; nf < 4; ++nf)
#pragma unroll
      for (int c = 0; c < 2; ++c)
        kf[nf][c] = *(const bf16x8*)&kp[(size_t)(kb2 * 64 + nf * 16 + lr) * 64 + c * 32 + lg * 8];

    f32x4 sv[2][4];
#pragma unroll
    for (int mf = 0; mf < 2; ++mf)
#pragma unroll
      for (int nf = 0; nf < 4; ++nf) {
        f32x4 z = {0.f, 0.f, 0.f, 0.f};
        z = __builtin_amdgcn_mfma_f32_16x16x32_bf16(qf[mf][0], kf[nf][0], z, 0, 0, 0);
        z = __builtin_amdgcn_mfma_f32_16x16x32_bf16(qf[mf][1], kf[nf][1], z, 0, 0, 0);
        sv[mf][nf] = z;
      }

    // scale + bias
#pragma unroll
    for (int mf = 0; mf < 2; ++mf)
#pragma unroll
      for (int nf = 0; nf < 4; ++nf)
#pragma unroll
        for (int r = 0; r < 4; ++r) {
          float bias = (float)pbs[wave * 32 + mf * 16 + lg * 4 + r][nf * 16 + lr];
          sv[mf][nf][r] = sv[mf][nf][r] * scale + bias;
        }

    // online softmax per q-row (rows live at (lg*4+r); cols across lr and nf)
#pragma unroll
    for (int mf = 0; mf < 2; ++mf)
#pragma unroll
      for (int r = 0; r < 4; ++r) {
        float tm = fmaxf(fmaxf(sv[mf][0][r], sv[mf][1][r]), fmaxf(sv[mf][2][r], sv[mf][3][r]));
#pragma unroll
        for (int x = 1; x < 16; x <<= 1) tm = fmaxf(tm, __shfl_xor(tm, x));
        float newm = fmaxf(mrow[mf][r], tm);
        float fs = __expf(mrow[mf][r] - newm);
        mrow[mf][r] = newm;
        float rs = 0.f;
#pragma unroll
        for (int nf = 0; nf < 4; ++nf) {
          float p = __expf(sv[mf][nf][r] - newm);
          sv[mf][nf][r] = p;
          rs += p;
        }
#pragma unroll
        for (int x = 1; x < 16; x <<= 1) rs += __shfl_xor(rs, x);
        lrow[mf][r] = lrow[mf][r] * fs + rs;
#pragma unroll
        for (int dn = 0; dn < 4; ++dn) of[mf][dn][r] *= fs;
      }

    // write P to per-wave LDS (re-layout D-frag -> A-frag)
#pragma unroll
    for (int mf = 0; mf < 2; ++mf)
#pragma unroll
      for (int nf = 0; nf < 4; ++nf)
#pragma unroll
        for (int r = 0; r < 4; ++r)
          pls[wave][mf * 16 + lg * 4 + r][nf * 16 + lr] = (__bf16)sv[mf][nf][r];
    __syncthreads();

    // PV
    bf16x8 pa[2][2], vf[4][2];
#pragma unroll
    for (int mf = 0; mf < 2; ++mf)
#pragma unroll
      for (int c = 0; c < 2; ++c)
        pa[mf][c] = *(const bf16x8*)&pls[wave][mf * 16 + lr][c * 32 + lg * 8];
#pragma unroll
    for (int dn = 0; dn < 4; ++dn)
#pragma unroll
      for (int c = 0; c < 2; ++c)
        vf[dn][c] = *(const bf16x8*)&vp[(size_t)(dn * 16 + lr) * 1024 + kb2 * 64 + c * 32 + lg * 8];
#pragma unroll
    for (int mf = 0; mf < 2; ++mf)
#pragma unroll
      for (int dn = 0; dn < 4; ++dn) {
        of[mf][dn] = __builtin_amdgcn_mfma_f32_16x16x32_bf16(pa[mf][0], vf[dn][0], of[mf][dn], 0, 0, 0);
        of[mf][dn] = __builtin_amdgcn_mfma_f32_16x16x32_bf16(pa[mf][1], vf[dn][1], of[mf][dn], 0, 0, 0);
      }
  }

  // epilogue: normalize and store merged [b*N+n][h*64+dd]
#pragma unroll
  for (int mf = 0; mf < 2; ++mf)
#pragma unroll
    for (int dn = 0; dn < 4; ++dn)
#pragma unroll
      for (int r = 0; r < 4; ++r) {
        int n = qw0 + mf * 16 + lg * 4 + r;
        int dd = dn * 16 + lr;
        float val = of[mf][dn][r] / lrow[mf][r];
        merged[((size_t)(b * 1024 + n)) * 512 + h * 64 + dd] = (__bf16)val;
      }
}

// ---------------- output projection GEMM: fp32 out + bias ----------------
__global__ __launch_bounds__(256) void out_gemm_kernel(const __bf16* __restrict__ A,
                                                       const __bf16* __restrict__ Bt,
                                                       const float* __restrict__ bo,
                                                       float* __restrict__ out) {
  int m0 = blockIdx.y * 128, n0 = blockIdx.x * 128;
  f32x4 acc[4][4];
  gemm_mainloop_128(A, Bt, 512, m0, n0, acc);
  int tid = threadIdx.x, wave = tid >> 6, lane = tid & 63;
  int wm = (wave >> 1) * 64, wn = (wave & 1) * 64, lg = lane >> 4, lr = lane & 15;
#pragma unroll
  for (int i = 0; i < 4; ++i)
#pragma unroll
    for (int j = 0; j < 4; ++j)
#pragma unroll
      for (int r = 0; r < 4; ++r) {
        int grow = m0 + wm + i * 16 + lg * 4 + r;
        int gcol = n0 + wn + j * 16 + lr;
        out[(size_t)grow * 512 + gcol] = acc[i][j][r] + bo[gcol];
      }
}

extern "C" void kernel_launch(void* const* d_in, const int* in_sizes, int n_in,
                              void* d_out, int out_size, void* d_ws, size_t ws_size,
                              hipStream_t stream) {
  const float* tokens = (const float*)d_in[0];
  const float* pf     = (const float*)d_in[1];
  const float* Wq     = (const float*)d_in[2];
  const float* bq     = (const float*)d_in[3];
  const float* Wk     = (const float*)d_in[4];
  const float* bk     = (const float*)d_in[5];
  const float* Wv     = (const float*)d_in[6];
  const float* bv     = (const float*)d_in[7];
  const float* Wo     = (const float*)d_in[8];
  const float* bo     = (const float*)d_in[9];
  const float* Wp     = (const float*)d_in[10];
  float* out = (float*)d_out;

  char* ws = (char*)d_ws;
  size_t off = 0;
  auto alloc = [&](size_t bytes) { char* p = ws + off; off += (bytes + 255) & ~(size_t)255; return p; };
  __bf16* tok_bf = (__bf16*)alloc((size_t)4096 * 512 * 2);
  __bf16* WcatT  = (__bf16*)alloc((size_t)1536 * 512 * 2);
  __bf16* WoT    = (__bf16*)alloc((size_t)512 * 512 * 2);
  __bf16* qb     = (__bf16*)alloc((size_t)32 * 1024 * 64 * 2);
  __bf16* kb     = (__bf16*)alloc((size_t)32 * 1024 * 64 * 2);
  __bf16* vtb    = (__bf16*)alloc((size_t)32 * 64 * 1024 * 2);
  __bf16* pbb    = (__bf16*)alloc((size_t)8 * 1024 * 1024 * 2);
  __bf16* merged = (__bf16*)alloc((size_t)4096 * 512 * 2);

  prep_kernel<<<PAIR_BLOCKS + CAST_BLOCKS + TR_BLOCKS, 256, 0, stream>>>(
      tokens, pf, Wq, Wk, Wv, Wo, Wp, tok_bf, WcatT, WoT, pbb);
  qkv_gemm_kernel<<<dim3(12, 32), 256, 0, stream>>>(tok_bf, WcatT, bq, bk, bv, qb, kb, vtb);
  flash_kernel<<<dim3(8, 32), 256, 0, stream>>>(qb, kb, vtb, pbb, merged);
  out_gemm_kernel<<<dim3(4, 32), 256, 0, stream>>>(merged, WoT, bo, out);
}